// Round 2
// baseline (146.402 us; speedup 1.0000x reference)
//
#include <hip/hip_runtime.h>
#include <hip/hip_cooperative_groups.h>

#define N_NODES 100000
#define N_EDGES 1000000
#define D 64
#define N_GRAPHS 512
#define NVEC (N_EDGES / 4)            // 250000 vec-edges (4 edges each)
#define DOT_ITEMS (N_NODES * 16)      // 16 threads per node
#define BLK 1024
#define GRID 256                      // 1 block/CU, co-resident for coop sync
#define NTHREADS (BLK * GRID)         // 262144

namespace cg = cooperative_groups;

// ---------------- fused cooperative kernel ----------------
// Phase 0: (a) prefetch this thread's vec-edge (ei/ea) into registers —
//              independent of y, so the 12 MB stream overlaps the x-stream;
//          (b) 2 binary searches PER BLOCK (distributed, so the 17-deep
//              dependent-load chain hides behind each block's 15 other waves)
//              -> lb[g] = lower_bound(batch, g);
//          (c) block 0 seeds out[g] = b.
// Phase 1: y[v] = dot(x[v,:], W), 16 threads/node, grid-stride (~6 iters).
// ---- grid.sync() ----
// Phase 2: gather y[src]/batch[dst], LDS histogram, flush with inv_cnt
//          scaling folded in (cnt = lb[g+1]-lb[g]).
__global__ __launch_bounds__(BLK, 4) void fused_kernel(
    const float* __restrict__ x, const float* __restrict__ W,
    const int* __restrict__ ei, const float* __restrict__ ea,
    const int* __restrict__ batch, const float* __restrict__ bptr,
    float* __restrict__ y, int* __restrict__ lb,
    float* __restrict__ out) {
    __shared__ float sacc[N_GRAPHS];
    const int tid = threadIdx.x;
    const int gt  = blockIdx.x * BLK + tid;

    if (tid < N_GRAPHS) sacc[tid] = 0.0f;
    if (blockIdx.x == 0 && tid < N_GRAPHS) out[tid] = bptr[0];

    // Phase 0a: edge prefetch into registers (12 regs/thread, 250000 threads)
    int4 s4, d4; float4 a4;
    const bool has_edge = gt < NVEC;
    if (has_edge) {
        s4 = reinterpret_cast<const int4*>(ei)[gt];
        d4 = reinterpret_cast<const int4*>(ei + N_EDGES)[gt];
        a4 = reinterpret_cast<const float4*>(ea)[gt];
    }

    // Phase 0b: distributed binary searches; block i covers g=2i, 2i+1;
    //           block 0 thread 2 covers g=512 (the upper sentinel).
    int sg = -1;
    if (tid < 2) sg = blockIdx.x * 2 + tid;
    else if (tid == 2 && blockIdx.x == 0) sg = N_GRAPHS;
    if (sg >= 0) {
        int lo = 0, hi = N_NODES;
        while (lo < hi) { int mid = (lo + hi) >> 1; if (batch[mid] < sg) lo = mid + 1; else hi = mid; }
        lb[sg] = lo;
    }

    // Phase 1: dot stream (25.6 MB), wave reads contiguous 1 KiB spans
    const int sub = tid & 15;
    const float4 wv = *reinterpret_cast<const float4*>(W + sub * 4);
    for (int t = gt; t < DOT_ITEMS; t += NTHREADS) {
        const int v = t >> 4;
        const float4 xv = *reinterpret_cast<const float4*>(x + (size_t)v * D + sub * 4);
        float p = xv.x * wv.x + xv.y * wv.y + xv.z * wv.z + xv.w * wv.w;
        p += __shfl_xor(p, 1, 64);
        p += __shfl_xor(p, 2, 64);
        p += __shfl_xor(p, 4, 64);
        p += __shfl_xor(p, 8, 64);
        if (sub == 0) y[v] = p;
    }

    // y, lb, out-seed now visible grid-wide
    cg::this_grid().sync();

    // Phase 2: gathers (L2-resident tables) + LDS histogram
    if (has_edge) {
        float m0 = a4.x * y[s4.x];  int g0 = batch[d4.x];
        float m1 = a4.y * y[s4.y];  int g1 = batch[d4.y];
        float m2 = a4.z * y[s4.z];  int g2 = batch[d4.z];
        float m3 = a4.w * y[s4.w];  int g3 = batch[d4.w];
        atomicAdd(&sacc[g0], m0);
        atomicAdd(&sacc[g1], m1);
        atomicAdd(&sacc[g2], m2);
        atomicAdd(&sacc[g3], m3);
    }
    __syncthreads();
    if (tid < N_GRAPHS) {
        float v = sacc[tid];
        float cnt = (float)(lb[tid + 1] - lb[tid]);
        if (v != 0.0f) atomicAdd(&out[tid], v * (1.0f / fmaxf(cnt, 1.0f)));
    }
}

// ---------------- fallback two-kernel path (proven R1 kernels) ----------------
#define DOT_BLOCKS (DOT_ITEMS / 256)
#define TAIL_BLOCKS 4
#define K2_THREADS 1024
#define K2_BLOCKS ((NVEC + K2_THREADS - 1) / K2_THREADS)

__global__ __launch_bounds__(256) void dot_kernel(const float* __restrict__ x,
                                                  const float* __restrict__ W,
                                                  const int* __restrict__ batch,
                                                  const float* __restrict__ bptr,
                                                  float* __restrict__ y,
                                                  float* __restrict__ inv_cnt,
                                                  float* __restrict__ out) {
    __shared__ int slb[132];
    if (blockIdx.x < DOT_BLOCKS) {
        int t = blockIdx.x * 256 + threadIdx.x;
        int v = t >> 4;
        int sub = t & 15;
        const float4 xv = *reinterpret_cast<const float4*>(x + (size_t)v * D + sub * 4);
        const float4 wv = *reinterpret_cast<const float4*>(W + sub * 4);
        float p = xv.x * wv.x + xv.y * wv.y + xv.z * wv.z + xv.w * wv.w;
        p += __shfl_xor(p, 1, 64);
        p += __shfl_xor(p, 2, 64);
        p += __shfl_xor(p, 4, 64);
        p += __shfl_xor(p, 8, 64);
        if (sub == 0) y[v] = p;
        return;
    }
    const int tb = blockIdx.x - DOT_BLOCKS;
    const int gbase = tb * 128;
    const int t = threadIdx.x;
    if (t <= 128) {
        const int target = gbase + t;
        int lo = 0, hi = N_NODES;
        while (lo < hi) { int mid = (lo + hi) >> 1; if (batch[mid] < target) lo = mid + 1; else hi = mid; }
        slb[t] = lo;
    }
    __syncthreads();
    if (t < 128) {
        const int g = gbase + t;
        float cnt = (float)(slb[t + 1] - slb[t]);
        inv_cnt[g] = 1.0f / fmaxf(cnt, 1.0f);
        out[g] = bptr[0];
    }
}

__global__ __launch_bounds__(K2_THREADS) void edge_kernel(const int* __restrict__ ei,
                                                          const float* __restrict__ ea,
                                                          const int* __restrict__ batch,
                                                          const float* __restrict__ y,
                                                          const float* __restrict__ inv_cnt,
                                                          float* __restrict__ out) {
    __shared__ float sacc[N_GRAPHS];
    const int tid = threadIdx.x;
    if (tid < N_GRAPHS) sacc[tid] = 0.0f;
    __syncthreads();
    int idx = blockIdx.x * K2_THREADS + tid;
    if (idx < NVEC) {
        const int4   s4 = reinterpret_cast<const int4*>(ei)[idx];
        const int4   d4 = reinterpret_cast<const int4*>(ei + N_EDGES)[idx];
        const float4 a4 = reinterpret_cast<const float4*>(ea)[idx];
        float m0 = a4.x * y[s4.x];  int g0 = batch[d4.x];
        float m1 = a4.y * y[s4.y];  int g1 = batch[d4.y];
        float m2 = a4.z * y[s4.z];  int g2 = batch[d4.z];
        float m3 = a4.w * y[s4.w];  int g3 = batch[d4.w];
        atomicAdd(&sacc[g0], m0);
        atomicAdd(&sacc[g1], m1);
        atomicAdd(&sacc[g2], m2);
        atomicAdd(&sacc[g3], m3);
    }
    __syncthreads();
    if (tid < N_GRAPHS) {
        float v = sacc[tid];
        if (v != 0.0f) atomicAdd(&out[tid], v * inv_cnt[tid]);
    }
}

extern "C" void kernel_launch(void* const* d_in, const int* in_sizes, int n_in,
                              void* d_out, int out_size, void* d_ws, size_t ws_size,
                              hipStream_t stream) {
    const float* x     = (const float*)d_in[0];  // [N, 64] fp32
    const int*   ei    = (const int*)  d_in[1];  // [2, E] int32
    const float* ea    = (const float*)d_in[2];  // [E] fp32
    const int*   batch = (const int*)  d_in[3];  // [N] int32, sorted
    const float* W     = (const float*)d_in[4];  // [1, 64] fp32
    const float* b     = (const float*)d_in[5];  // [1] fp32
    float* out = (float*)d_out;                  // [G, 1] = 512 fp32

    float* y       = (float*)d_ws;               // N_NODES floats
    int*   lb      = (int*)(y + N_NODES);        // N_GRAPHS+1 ints
    float* inv_cnt = (float*)(lb + N_GRAPHS + 4);// fallback only

    void* args[] = {(void*)&x, (void*)&W, (void*)&ei, (void*)&ea,
                    (void*)&batch, (void*)&b, (void*)&y, (void*)&lb, (void*)&out};
    hipError_t err = hipLaunchCooperativeKernel((const void*)fused_kernel,
                                                dim3(GRID), dim3(BLK), args, 0, stream);
    if (err != hipSuccess) {
        // fallback: proven two-kernel path
        dot_kernel<<<DOT_BLOCKS + TAIL_BLOCKS, 256, 0, stream>>>(
            x, W, batch, b, y, inv_cnt, out);
        edge_kernel<<<K2_BLOCKS, K2_THREADS, 0, stream>>>(ei, ea, batch, y, inv_cnt, out);
    }
}

// Round 3
// 106.028 us; speedup vs baseline: 1.3808x; 1.3808x over previous
//
#include <hip/hip_runtime.h>

#define N_NODES 100000
#define N_EDGES 1000000
#define D 64
#define N_GRAPHS 512
#define DOT_THREADS (N_NODES * 16)        // 16 threads per node
#define DOT_BLOCKS (DOT_THREADS / 256)    // 6250, exact
#define TAIL_BLOCKS 4                     // 4 blocks x 128 graphs
#define K2_THREADS 1024
#define K2_BLOCKS ((N_EDGES / 4 + K2_THREADS - 1) / K2_THREADS)  // 245

// clang ext-vector types so __builtin_nontemporal_load accepts them
typedef float f4 __attribute__((ext_vector_type(4)));
typedef int   i4 __attribute__((ext_vector_type(4)));

// K1: y[v] = dot(x[v,:], W)  (16 threads/node, float4 each — wave reads a
//     fully-contiguous 1 KiB span: 4 nodes x 256 B). x is read ONCE ->
//     non-temporal load keeps it from evicting y/batch lines K2 needs.
//     + 4 tail blocks hidden under the 25.6 MB x-stream:
//       ONE binary search per thread (lower_bound shared via LDS with the
//       t+1 neighbor), writes inv_cnt[g] and seeds out[g] = b.
// NOTE (R2 lesson): do NOT fuse K1+K2 with cg::grid().sync() — the grid
// barrier's device-scope fence across 8 non-coherent XCD L2s costs ~35-40 us
// (52 us fused vs ~17 us split). The kernel-launch boundary IS the cheap
// barrier on gfx950.
__global__ __launch_bounds__(256) void dot_kernel(const float* __restrict__ x,
                                                  const float* __restrict__ W,
                                                  const int* __restrict__ batch,
                                                  const float* __restrict__ bptr,
                                                  float* __restrict__ y,
                                                  float* __restrict__ inv_cnt,
                                                  float* __restrict__ out) {
    __shared__ int slb[132];   // 129 used; dot blocks never touch it
    if (blockIdx.x < DOT_BLOCKS) {
        int t = blockIdx.x * 256 + threadIdx.x;
        int v = t >> 4;      // node index
        int sub = t & 15;    // 16 sub-lanes cover 64 floats via float4
        const f4 xv = __builtin_nontemporal_load(
            reinterpret_cast<const f4*>(x + (size_t)v * D + sub * 4));
        const f4 wv = *reinterpret_cast<const f4*>(W + sub * 4);
        float p = xv.x * wv.x + xv.y * wv.y + xv.z * wv.z + xv.w * wv.w;
        p += __shfl_xor(p, 1, 64);
        p += __shfl_xor(p, 2, 64);
        p += __shfl_xor(p, 4, 64);
        p += __shfl_xor(p, 8, 64);
        if (sub == 0) y[v] = p;
        return;
    }
    // tail block tb covers graphs [tb*128, tb*128+128)
    const int tb = blockIdx.x - DOT_BLOCKS;
    const int gbase = tb * 128;
    const int t = threadIdx.x;
    if (t <= 128) {
        // slb[t] = lower_bound(batch, gbase + t) — 17 dependent loads, L2-warm
        const int target = gbase + t;
        int lo = 0, hi = N_NODES;
        while (lo < hi) {
            int mid = (lo + hi) >> 1;
            if (batch[mid] < target) lo = mid + 1; else hi = mid;
        }
        slb[t] = lo;
    }
    __syncthreads();
    if (t < 128) {
        const int g = gbase + t;
        float cnt = (float)(slb[t + 1] - slb[t]);
        inv_cnt[g] = 1.0f / fmaxf(cnt, 1.0f);
        out[g] = bptr[0];    // seed with bias; K2 atomically accumulates
    }
}

// K2: per-block LDS histogram of edge_attr[e]*y[src_e] into graph bins;
//     flush applies inv_cnt scaling and adds straight into out.
//     ei/ea are single-use streams -> non-temporal loads preserve L2
//     residency of the y (400 KB) and batch (400 KB) gather tables.
//     NO fences/counters — device-scope fence machinery costs ~76 us.
__global__ __launch_bounds__(K2_THREADS) void edge_kernel(const int* __restrict__ ei,
                                                          const float* __restrict__ ea,
                                                          const int* __restrict__ batch,
                                                          const float* __restrict__ y,
                                                          const float* __restrict__ inv_cnt,
                                                          float* __restrict__ out) {
    __shared__ float sacc[N_GRAPHS];
    const int tid = threadIdx.x;
    if (tid < N_GRAPHS) sacc[tid] = 0.0f;
    __syncthreads();

    // 4 edges per thread via 16B nt loads; 250000 vec-edges over 245x1024
    int idx = blockIdx.x * K2_THREADS + tid;
    if (idx < N_EDGES / 4) {
        const i4 s4 = __builtin_nontemporal_load(reinterpret_cast<const i4*>(ei) + idx);
        const i4 d4 = __builtin_nontemporal_load(reinterpret_cast<const i4*>(ei + N_EDGES) + idx);
        const f4 a4 = __builtin_nontemporal_load(reinterpret_cast<const f4*>(ea) + idx);
        // 4 independent gather pairs -> ILP hides L2 latency
        float m0 = a4.x * y[s4.x];  int g0 = batch[d4.x];
        float m1 = a4.y * y[s4.y];  int g1 = batch[d4.y];
        float m2 = a4.z * y[s4.z];  int g2 = batch[d4.z];
        float m3 = a4.w * y[s4.w];  int g3 = batch[d4.w];
        atomicAdd(&sacc[g0], m0);
        atomicAdd(&sacc[g1], m1);
        atomicAdd(&sacc[g2], m2);
        atomicAdd(&sacc[g3], m3);
    }
    __syncthreads();
    if (tid < N_GRAPHS) {
        float v = sacc[tid];
        if (v != 0.0f) atomicAdd(&out[tid], v * inv_cnt[tid]);
    }
}

extern "C" void kernel_launch(void* const* d_in, const int* in_sizes, int n_in,
                              void* d_out, int out_size, void* d_ws, size_t ws_size,
                              hipStream_t stream) {
    const float* x     = (const float*)d_in[0];  // [N, 64] fp32
    const int*   ei    = (const int*)  d_in[1];  // [2, E] int32
    const float* ea    = (const float*)d_in[2];  // [E] fp32
    const int*   batch = (const int*)  d_in[3];  // [N] int32, sorted
    const float* W     = (const float*)d_in[4];  // [1, 64] fp32
    const float* b     = (const float*)d_in[5];  // [1] fp32
    float* out = (float*)d_out;                  // [G, 1] = 512 fp32

    float* y       = (float*)d_ws;               // N_NODES floats
    float* inv_cnt = y + N_NODES;                // N_GRAPHS floats

    // K1: 6250 dot blocks + 4 tail blocks (inv_cnt + out=b seed)
    dot_kernel<<<DOT_BLOCKS + TAIL_BLOCKS, 256, 0, stream>>>(
        x, W, batch, b, y, inv_cnt, out);
    // K2: 245 blocks x 1024 threads, accumulates scaled sums into out
    edge_kernel<<<K2_BLOCKS, K2_THREADS, 0, stream>>>(ei, ea, batch, y, inv_cnt, out);
}

// Round 4
// 104.598 us; speedup vs baseline: 1.3997x; 1.0137x over previous
//
#include <hip/hip_runtime.h>

#define N_NODES 100000
#define N_EDGES 1000000
#define D 64
#define N_GRAPHS 512
#define DOT_THREADS (N_NODES * 16)        // 16 threads per node
#define DOT_BLOCKS (DOT_THREADS / 256)    // 6250, exact
#define TAIL_BLOCKS 4                     // 4 blocks x 128 graphs
#define K2_THREADS 1024
#define K2_BLOCKS ((N_EDGES / 4 + K2_THREADS - 1) / K2_THREADS)  // 245

// R3 lesson: NO non-temporal loads — nt bypasses L2 on gfx950, which raised
// stream-load latency and cost +3.6 us. The gather tables (800 KB) were never
// under eviction pressure in 8x4 MiB of L2.
// R2 lesson: NO cg::grid().sync() fusion — device-scope barrier across 8
// non-coherent XCD L2s costs ~35-40 us; the kernel-launch boundary IS the
// cheap grid barrier on this chip.

// K1: y[v] = dot(x[v,:], W)  (16 threads/node, float4 each — wave reads a
//     fully-contiguous 1 KiB span: 4 nodes x 256 B).
//     + 4 tail blocks hidden under the 25.6 MB x-stream:
//       ONE binary search per thread (lower_bound shared via LDS with the
//       t+1 neighbor -> dependent-load chain halved vs 2 searches/thread),
//       writes inv_cnt[g] and seeds out[g] = b (no separate finalize kernel).
__global__ __launch_bounds__(256) void dot_kernel(const float* __restrict__ x,
                                                  const float* __restrict__ W,
                                                  const int* __restrict__ batch,
                                                  const float* __restrict__ bptr,
                                                  float* __restrict__ y,
                                                  float* __restrict__ inv_cnt,
                                                  float* __restrict__ out) {
    __shared__ int slb[132];   // 129 used; dot blocks never touch it
    if (blockIdx.x < DOT_BLOCKS) {
        int t = blockIdx.x * 256 + threadIdx.x;
        int v = t >> 4;      // node index
        int sub = t & 15;    // 16 sub-lanes cover 64 floats via float4
        const float4 xv = *reinterpret_cast<const float4*>(x + (size_t)v * D + sub * 4);
        const float4 wv = *reinterpret_cast<const float4*>(W + sub * 4);
        float p = xv.x * wv.x + xv.y * wv.y + xv.z * wv.z + xv.w * wv.w;
        p += __shfl_xor(p, 1, 64);
        p += __shfl_xor(p, 2, 64);
        p += __shfl_xor(p, 4, 64);
        p += __shfl_xor(p, 8, 64);
        if (sub == 0) y[v] = p;
        return;
    }
    // tail block tb covers graphs [tb*128, tb*128+128)
    const int tb = blockIdx.x - DOT_BLOCKS;
    const int gbase = tb * 128;
    const int t = threadIdx.x;
    if (t <= 128) {
        // slb[t] = lower_bound(batch, gbase + t) — 17 dependent loads, L2-warm
        const int target = gbase + t;
        int lo = 0, hi = N_NODES;
        while (lo < hi) {
            int mid = (lo + hi) >> 1;
            if (batch[mid] < target) lo = mid + 1; else hi = mid;
        }
        slb[t] = lo;
    }
    __syncthreads();
    if (t < 128) {
        const int g = gbase + t;
        float cnt = (float)(slb[t + 1] - slb[t]);
        inv_cnt[g] = 1.0f / fmaxf(cnt, 1.0f);
        out[g] = bptr[0];    // seed with bias; K2 atomically accumulates
    }
}

// K2: per-block LDS histogram of edge_attr[e]*y[src_e] into graph bins;
//     flush applies inv_cnt scaling and adds straight into out.
//     NO fences/counters — device-scope fence machinery costs ~76 us.
__global__ __launch_bounds__(K2_THREADS) void edge_kernel(const int* __restrict__ ei,
                                                          const float* __restrict__ ea,
                                                          const int* __restrict__ batch,
                                                          const float* __restrict__ y,
                                                          const float* __restrict__ inv_cnt,
                                                          float* __restrict__ out) {
    __shared__ float sacc[N_GRAPHS];
    const int tid = threadIdx.x;
    if (tid < N_GRAPHS) sacc[tid] = 0.0f;
    __syncthreads();

    // 4 edges per thread via 16B loads; 250000 vec-edges over 245x1024 threads
    int idx = blockIdx.x * K2_THREADS + tid;
    if (idx < N_EDGES / 4) {
        const int4   s4 = reinterpret_cast<const int4*>(ei)[idx];
        const int4   d4 = reinterpret_cast<const int4*>(ei + N_EDGES)[idx];
        const float4 a4 = reinterpret_cast<const float4*>(ea)[idx];
        // 4 independent gather pairs -> ILP hides L2 latency
        float m0 = a4.x * y[s4.x];  int g0 = batch[d4.x];
        float m1 = a4.y * y[s4.y];  int g1 = batch[d4.y];
        float m2 = a4.z * y[s4.z];  int g2 = batch[d4.z];
        float m3 = a4.w * y[s4.w];  int g3 = batch[d4.w];
        atomicAdd(&sacc[g0], m0);
        atomicAdd(&sacc[g1], m1);
        atomicAdd(&sacc[g2], m2);
        atomicAdd(&sacc[g3], m3);
    }
    __syncthreads();
    if (tid < N_GRAPHS) {
        float v = sacc[tid];
        if (v != 0.0f) atomicAdd(&out[tid], v * inv_cnt[tid]);
    }
}

extern "C" void kernel_launch(void* const* d_in, const int* in_sizes, int n_in,
                              void* d_out, int out_size, void* d_ws, size_t ws_size,
                              hipStream_t stream) {
    const float* x     = (const float*)d_in[0];  // [N, 64] fp32
    const int*   ei    = (const int*)  d_in[1];  // [2, E] int32
    const float* ea    = (const float*)d_in[2];  // [E] fp32
    const int*   batch = (const int*)  d_in[3];  // [N] int32, sorted
    const float* W     = (const float*)d_in[4];  // [1, 64] fp32
    const float* b     = (const float*)d_in[5];  // [1] fp32
    float* out = (float*)d_out;                  // [G, 1] = 512 fp32

    float* y       = (float*)d_ws;               // N_NODES floats
    float* inv_cnt = y + N_NODES;                // N_GRAPHS floats

    // K1: 6250 dot blocks + 4 tail blocks (inv_cnt + out=b seed)
    dot_kernel<<<DOT_BLOCKS + TAIL_BLOCKS, 256, 0, stream>>>(
        x, W, batch, b, y, inv_cnt, out);
    // K2: 245 blocks x 1024 threads, accumulates scaled sums into out
    edge_kernel<<<K2_BLOCKS, K2_THREADS, 0, stream>>>(ei, ea, batch, y, inv_cnt, out);
}